// Round 5
// baseline (228.920 us; speedup 1.0000x reference)
//
#include <hip/hip_runtime.h>
#include <math.h>
#include <stdint.h>

#define C_ 256
#define HW_ 4096
#define PLANE (C_*HW_)   // 1048576 elements per batch
#define INV_CNT (1.f / 131072.f)

typedef __attribute__((ext_vector_type(8))) short bf16x8;
typedef __attribute__((ext_vector_type(4))) float f32x4;

__device__ __forceinline__ unsigned short f2bf(float f) {
    union { float f; unsigned int u; } v; v.f = f;
    unsigned int r = v.u + 0x7fffu + ((v.u >> 16) & 1u);
    return (unsigned short)(r >> 16);
}

__device__ __forceinline__ void load_lds16(const void* g, void* l) {
    __builtin_amdgcn_global_load_lds(
        (const __attribute__((address_space(1))) unsigned int*)g,
        (__attribute__((address_space(3))) unsigned int*)l, 16, 0, 0);
}

// ---------------------------------------------------------------------------
// Weight convert + zero the stats buffer (runs first each call; ws is poisoned)
// ---------------------------------------------------------------------------
__global__ __launch_bounds__(256) void wcvt_kernel(
    const float* __restrict__ wq, const float* __restrict__ wk,
    const float* __restrict__ wv, const float* __restrict__ wp,
    unsigned short* __restrict__ dst, float* __restrict__ stats)
{
    int idx = blockIdx.x * 256 + threadIdx.x;   // 262144 total
    const float* s = (idx < 65536) ? wq : (idx < 131072) ? wk
                   : (idx < 196608) ? wv : wp;
    dst[idx] = f2bf(s[idx & 65535]);
    if (blockIdx.x == 0 && threadIdx.x < 192) stats[threadIdx.x] = 0.f;
}

// ---------------------------------------------------------------------------
// Transpose + convert: x fp32 [b][256][4096] -> xT bf16 [b][4096][256]
// ---------------------------------------------------------------------------
__global__ __launch_bounds__(256) void transpose_cvt_kernel(
    const float* __restrict__ src, unsigned short* __restrict__ dst)
{
    __shared__ float tile[64][65];
    int b = blockIdx.z;
    const float* s = src + (size_t)b * PLANE;
    unsigned short* d = dst + (size_t)b * PLANE;
    int c0 = blockIdx.y * 64, n0 = blockIdx.x * 64;
    int t = threadIdx.x;
    int r = t >> 6, col = t & 63;
#pragma unroll
    for (int i = 0; i < 16; i++)
        tile[r + i * 4][col] = s[(size_t)(c0 + r + i * 4) * HW_ + n0 + col];
    __syncthreads();
#pragma unroll
    for (int i = 0; i < 16; i++)
        d[(size_t)(n0 + r + i * 4) * 256 + c0 + col] = f2bf(tile[col][r + i * 4]);
}

// ---------------------------------------------------------------------------
// Transpose + add attn(bf16 token-major) + convert:
// aT[n][c] = bf16( pos[c][n] + atok[n][c] )
// ---------------------------------------------------------------------------
__global__ __launch_bounds__(256) void transpose_cvt_add_kernel(
    const float* __restrict__ pos, const unsigned short* __restrict__ attn,
    unsigned short* __restrict__ dst)
{
    __shared__ float tile[64][65];
    int b = blockIdx.z;
    const float* s = pos + (size_t)b * PLANE;
    const unsigned short* a = attn + (size_t)b * PLANE;
    unsigned short* d = dst + (size_t)b * PLANE;
    int c0 = blockIdx.y * 64, n0 = blockIdx.x * 64;
    int t = threadIdx.x;
    int r = t >> 6, col = t & 63;
#pragma unroll
    for (int i = 0; i < 16; i++)
        tile[r + i * 4][col] = s[(size_t)(c0 + r + i * 4) * HW_ + n0 + col];
    __syncthreads();
#pragma unroll
    for (int i = 0; i < 16; i++) {
        size_t o = (size_t)(n0 + r + i * 4) * 256 + c0 + col;
        float av = __uint_as_float(((unsigned)a[o]) << 16);
        d[o] = f2bf(tile[col][r + i * 4] + av);
    }
}

// ---------------------------------------------------------------------------
// MFMA core: acc[mi][ni] (4x4 frags of 16x16x32) for C = A * B^T tile.
// ---------------------------------------------------------------------------
__device__ __forceinline__ void mfma_core(
    const unsigned short* __restrict__ A,
    const unsigned short* __restrict__ Bm,
    int m0, int n0, f32x4 (&acc)[4][4])
{
    __shared__ unsigned short As[128 * 32];
    __shared__ unsigned short Bs[128 * 32];
    const int t = threadIdx.x;
    const int lane = t & 63, wave = t >> 6;

#pragma unroll
    for (int i = 0; i < 4; i++)
#pragma unroll
        for (int j = 0; j < 4; j++) acc[i][j] = (f32x4)0.f;

    const int srow = wave * 32 + (lane >> 2);
    const int scol = (lane & 3) * 8;
    const unsigned short* ga = A  + (size_t)(m0 + srow) * 256 + scol;
    const unsigned short* gb = Bm + (size_t)(n0 + srow) * 256 + scol;
    unsigned short* la = As + (wave * 32) * 32;
    unsigned short* lb = Bs + (wave * 32) * 32;

    const int wm = wave >> 1, wn = wave & 1;
    const int fr = lane & 15, kg = lane >> 4;

    for (int k0 = 0; k0 < 256; k0 += 32) {
        if (k0) __syncthreads();
        load_lds16(ga + k0,             la);
        load_lds16(ga + k0 + 16 * 256,  la + 16 * 32);
        load_lds16(gb + k0,             lb);
        load_lds16(gb + k0 + 16 * 256,  lb + 16 * 32);
        __syncthreads();

        bf16x8 af[4], bfr[4];
#pragma unroll
        for (int i = 0; i < 4; i++) {
            af[i]  = *(const bf16x8*)(As + (wm * 64 + i * 16 + fr) * 32 + kg * 8);
            bfr[i] = *(const bf16x8*)(Bs + (wn * 64 + i * 16 + fr) * 32 + kg * 8);
        }
#pragma unroll
        for (int mi = 0; mi < 4; mi++)
#pragma unroll
            for (int ni = 0; ni < 4; ni++)
                acc[mi][ni] = __builtin_amdgcn_mfma_f32_16x16x32_bf16(
                    af[mi], bfr[ni], acc[mi][ni], 0, 0, 0);
    }
}

// wave-reduce 2 (sum,sumsq) pairs, lane 0 atomics into stats
__device__ __forceinline__ void stat_atomic(
    float s0, float ss0, float s1, float ss1, float* d0, float* d1)
{
#pragma unroll
    for (int off = 32; off >= 1; off >>= 1) {
        s0  += __shfl_down(s0, off);  ss0 += __shfl_down(ss0, off);
        s1  += __shfl_down(s1, off);  ss1 += __shfl_down(ss1, off);
    }
    if ((threadIdx.x & 63) == 0) {
        atomicAdd(d0, s0); atomicAdd(d0 + 1, ss0);
        atomicAdd(d1, s1); atomicAdd(d1 + 1, ss1);
    }
}

// ---------------------------------------------------------------------------
// q/k/v: C[token][outch] bf16, + GN sum/sumsq atomics for q,k. grid (2,32,12)
// ---------------------------------------------------------------------------
__global__ __launch_bounds__(256) void gemm_qkv_mfma(
    const unsigned short* __restrict__ wbf, const unsigned short* __restrict__ xT,
    unsigned short* __restrict__ q, unsigned short* __restrict__ k,
    unsigned short* __restrict__ v, float* __restrict__ stats)
{
    int z = blockIdx.z;
    int batch = z & 3, which = z >> 2;
    unsigned short* Y = ((which == 0) ? q : (which == 1) ? k : v)
                        + (size_t)batch * PLANE;
    const unsigned short* A = xT + (size_t)batch * PLANE;
    const unsigned short* Bm = wbf + which * 65536;
    const int n0 = blockIdx.x * 128;   // outch
    const int m0 = blockIdx.y * 128;   // token

    f32x4 acc[4][4];
    mfma_core(A, Bm, m0, n0, acc);

    const int lane = threadIdx.x & 63, wave = threadIdx.x >> 6;
    const int wm = wave >> 1, wn = wave & 1;
    const int cl = lane & 15, qd = lane >> 4;

    // GN partial sums for q/k: group = outch/32 -> local gl = (ni>>1)
    if (which < 2) {
        float s[2] = {0.f, 0.f}, ss[2] = {0.f, 0.f};
#pragma unroll
        for (int mi = 0; mi < 4; mi++)
#pragma unroll
            for (int ni = 0; ni < 4; ni++)
#pragma unroll
                for (int r = 0; r < 4; r++) {
                    float vv = acc[mi][ni][r];
                    s[ni >> 1] += vv; ss[ni >> 1] += vv * vv;
                }
        int gbase = which * 64 + (batch * 8 + (n0 >> 5) + wn * 2) * 2;
        stat_atomic(s[0], ss[0], s[1], ss[1], stats + gbase, stats + gbase + 2);
    }

#pragma unroll
    for (int mi = 0; mi < 4; mi++)
#pragma unroll
        for (int r = 0; r < 4; r++) {
            int grow = m0 + wm * 64 + mi * 16 + qd * 4 + r;   // token
#pragma unroll
            for (int ni = 0; ni < 4; ni++) {
                int gcol = n0 + wn * 64 + ni * 16 + cl;       // outch
                Y[(size_t)grow * 256 + gcol] = f2bf(acc[mi][ni][r]);
            }
        }
}

// ---------------------------------------------------------------------------
// final projection: C[outch][token] fp32 + bias, + GN sum/sumsq atomics.
// grid (32, 2, 4)
// ---------------------------------------------------------------------------
__global__ __launch_bounds__(256) void gemm_out_mfma(
    const unsigned short* __restrict__ wbf, const unsigned short* __restrict__ aT,
    const float* __restrict__ bp, float* __restrict__ y, float* __restrict__ stats)
{
    int batch = blockIdx.z;
    const unsigned short* A = wbf + 3 * 65536;
    const unsigned short* Bm = aT + (size_t)batch * PLANE;
    float* Y = y + (size_t)batch * PLANE;
    const int n0 = blockIdx.x * 128;   // token
    const int m0 = blockIdx.y * 128;   // outch

    f32x4 acc[4][4];
    mfma_core(A, Bm, m0, n0, acc);

    const int lane = threadIdx.x & 63, wave = threadIdx.x >> 6;
    const int wm = wave >> 1, wn = wave & 1;
    const int cl = lane & 15, qd = lane >> 4;

    float s[2] = {0.f, 0.f}, ss[2] = {0.f, 0.f};
#pragma unroll
    for (int mi = 0; mi < 4; mi++) {
#pragma unroll
        for (int r = 0; r < 4; r++) {
            int grow = m0 + wm * 64 + mi * 16 + qd * 4 + r;   // outch
            float bb = bp[grow];
#pragma unroll
            for (int ni = 0; ni < 4; ni++) {
                int gcol = n0 + wn * 64 + ni * 16 + cl;       // token
                float vv = acc[mi][ni][r] + bb;
                s[mi >> 1] += vv; ss[mi >> 1] += vv * vv;
                Y[(size_t)grow * HW_ + gcol] = vv;
            }
        }
    }
    int gbase = 128 + (batch * 8 + (m0 >> 5) + wm * 2) * 2;
    stat_atomic(s[0], ss[0], s[1], ss[1], stats + gbase, stats + gbase + 2);
}

// ---------------------------------------------------------------------------
// Attention, token-major bf16 in/out. Thread = one (pixel, head).
// ---------------------------------------------------------------------------
__device__ __forceinline__ void bf16x32_load(const unsigned short* p, float* o) {
    const uint4* u4 = (const uint4*)p;
#pragma unroll
    for (int i = 0; i < 4; i++) {
        uint4 u = u4[i];
        o[i*8+0] = __uint_as_float(u.x << 16); o[i*8+1] = __uint_as_float(u.x & 0xffff0000u);
        o[i*8+2] = __uint_as_float(u.y << 16); o[i*8+3] = __uint_as_float(u.y & 0xffff0000u);
        o[i*8+4] = __uint_as_float(u.z << 16); o[i*8+5] = __uint_as_float(u.z & 0xffff0000u);
        o[i*8+6] = __uint_as_float(u.w << 16); o[i*8+7] = __uint_as_float(u.w & 0xffff0000u);
    }
}

__global__ __launch_bounds__(256) void attn_tok_kernel(
    const unsigned short* __restrict__ qtok, const unsigned short* __restrict__ ktok,
    const unsigned short* __restrict__ vtok, const float* __restrict__ stats,
    const float* __restrict__ gqg, const float* __restrict__ gqb,
    const float* __restrict__ gkg, const float* __restrict__ gkb,
    unsigned short* __restrict__ out)
{
    __shared__ float sqg[256], sqb[256], skg[256], skb[256];
    const int t = threadIdx.x;
    sqg[t] = gqg[t]; sqb[t] = gqb[t]; skg[t] = gkg[t]; skb[t] = gkb[t];
    __syncthreads();

    const int h = t & 7;
    const int pix = blockIdx.x * 32 + (t >> 3);   // 0..16383
    const int b = pix >> 12;
    const size_t base = (size_t)pix * 256 + h * 32;
    const int sg = (b * 8 + h) * 2;
    const float K2 = 0.17677669529663687f * 1.4426950408889634f; // scale*log2e

    float a[32], kn[32], vv[32];

    // Q
    {
        float S = stats[sg], SS = stats[sg + 1];
        float m = S * INV_CNT;
        float r = rsqrtf(SS * INV_CNT - m * m + 1e-5f);
        float qv[32], ssum = 0.f;
        bf16x32_load(qtok + base, qv);
#pragma unroll
        for (int j = 0; j < 32; j++) {
            float g = r * sqg[h * 32 + j];
            qv[j] = (qv[j] - m) * g + sqb[h * 32 + j];
            ssum = fmaf(qv[j], qv[j], ssum);
        }
        float inv = K2 / fmaxf(sqrtf(ssum), 1e-12f);
#pragma unroll
        for (int j = 0; j < 32; j++) a[j] = qv[j] * inv;
    }
    // K
    {
        float S = stats[64 + sg], SS = stats[64 + sg + 1];
        float m = S * INV_CNT;
        float r = rsqrtf(SS * INV_CNT - m * m + 1e-5f);
        float ssum = 0.f;
        bf16x32_load(ktok + base, kn);
#pragma unroll
        for (int j = 0; j < 32; j++) {
            float g = r * skg[h * 32 + j];
            kn[j] = (kn[j] - m) * g + skb[h * 32 + j];
            ssum = fmaf(kn[j], kn[j], ssum);
        }
        float inv = 1.f / fmaxf(sqrtf(ssum), 1e-12f);
#pragma unroll
        for (int j = 0; j < 32; j++) kn[j] *= inv;
    }
    bf16x32_load(vtok + base, vv);

    // 32x32 softmax-weighted sum -> bf16 out
    uint4* op = (uint4*)(out + base);
#pragma unroll
    for (int di = 0; di < 4; di++) {
        unsigned int od[4];
#pragma unroll
        for (int dp = 0; dp < 4; dp++) {
            float o2[2];
#pragma unroll
            for (int dd = 0; dd < 2; dd++) {
                float ad = a[di * 8 + dp * 2 + dd];
                float num = 0.f, den = 0.f;
#pragma unroll
                for (int e = 0; e < 32; e++) {
                    float w = __builtin_amdgcn_exp2f(ad * kn[e]);
                    num = fmaf(w, vv[e], num);
                    den += w;
                }
                o2[dd] = num / den;
            }
            od[dp] = (unsigned)f2bf(o2[0]) | ((unsigned)f2bf(o2[1]) << 16);
        }
        op[di] = make_uint4(od[0], od[1], od[2], od[3]);
    }
}

// ---------------------------------------------------------------------------
// Fused depthwise 3x3 -> GELU -> depthwise 3x3. One (b,c) plane per block.
// ---------------------------------------------------------------------------
__device__ __forceinline__ float gelu_exact(float v) {
    return 0.5f * v * (1.f + erff(v * 0.70710678118654752f));
}

__global__ __launch_bounds__(256) void dwconv_fused_kernel(
    const float* __restrict__ x,
    const float* __restrict__ dw1, const float* __restrict__ db1,
    const float* __restrict__ dw2, const float* __restrict__ db2,
    float* __restrict__ pos)
{
    __shared__ float xs[66 * 68];
    __shared__ float ps[66 * 68];
    const int bc = blockIdx.x;      // b*256 + c
    const int c = bc & 255;
    const int t = threadIdx.x;
    const float* plane = x + (size_t)bc * 4096;

    float w1[9], w2[9];
#pragma unroll
    for (int i = 0; i < 9; i++) { w1[i] = dw1[c * 9 + i]; w2[i] = dw2[c * 9 + i]; }
    const float b1 = db1[c], b2 = db2[c];

    for (int i = t; i < 66 * 66; i += 256) {
        int r = i / 66, cc = i - r * 66;
        int gr = r - 1, gc = cc - 1;
        float v = 0.f;
        if ((unsigned)gr < 64u && (unsigned)gc < 64u) v = plane[gr * 64 + gc];
        xs[r * 68 + cc] = v;
    }
    __syncthreads();

    for (int i = t; i < 66 * 66; i += 256) {
        int pr = i / 66, pc = i - pr * 66;
        int gr = pr - 1, gc = pc - 1;
        float val = 0.f;
        if ((unsigned)gr < 64u && (unsigned)gc < 64u) {
            float s = b1;
#pragma unroll
            for (int ky = 0; ky < 3; ky++)
#pragma unroll
                for (int kx = 0; kx < 3; kx++)
                    s += w1[ky * 3 + kx] * xs[(gr + ky) * 68 + (gc + kx)];
            val = gelu_exact(s);
        }
        ps[pr * 68 + pc] = val;
    }
    __syncthreads();

    for (int i = t; i < 4096; i += 256) {
        int orow = i >> 6, ocol = i & 63;
        float s = b2;
#pragma unroll
        for (int ky = 0; ky < 3; ky++)
#pragma unroll
            for (int kx = 0; kx < 3; kx++)
                s += w2[ky * 3 + kx] * ps[(orow + ky) * 68 + (ocol + kx)];
        pos[(size_t)bc * 4096 + i] = s;
    }
}

// ---------------------------------------------------------------------------
// Final GroupNorm apply (in place on d_out), mean/rstd from raw sums
// ---------------------------------------------------------------------------
__global__ __launch_bounds__(256) void gn_apply_kernel(
    float* __restrict__ y, const float* __restrict__ stats,
    const float* __restrict__ gamma, const float* __restrict__ beta)
{
    int i4 = blockIdx.x * 256 + threadIdx.x;
    int idx = i4 * 4;
    int c = (idx >> 12) & 255;
    int bg = ((idx >> 20) << 3) | (c >> 5);
    float S = stats[128 + bg * 2], SS = stats[128 + bg * 2 + 1];
    float mean = S * INV_CNT;
    float rstd = rsqrtf(SS * INV_CNT - mean * mean + 1e-5f);
    float ga = rstd * gamma[c], be = beta[c] - mean * ga;
    float4 v4 = *(float4*)&y[idx];
    v4.x = v4.x * ga + be;
    v4.y = v4.y * ga + be;
    v4.z = v4.z * ga + be;
    v4.w = v4.w * ga + be;
    *(float4*)&y[idx] = v4;
}

// ---------------------------------------------------------------------------
extern "C" void kernel_launch(void* const* d_in, const int* in_sizes, int n_in,
                              void* d_out, int out_size, void* d_ws, size_t ws_size,
                              hipStream_t stream)
{
    const float* x   = (const float*)d_in[0];
    const float* wq  = (const float*)d_in[1];
    const float* gqg = (const float*)d_in[2];
    const float* gqb = (const float*)d_in[3];
    const float* wk  = (const float*)d_in[4];
    const float* gkg = (const float*)d_in[5];
    const float* gkb = (const float*)d_in[6];
    const float* wv  = (const float*)d_in[7];
    const float* wp  = (const float*)d_in[8];
    const float* bp  = (const float*)d_in[9];
    const float* gpg = (const float*)d_in[10];
    const float* gpb = (const float*)d_in[11];
    const float* dw1 = (const float*)d_in[12];
    const float* db1 = (const float*)d_in[13];
    const float* dw2 = (const float*)d_in[14];
    const float* db2 = (const float*)d_in[15];
    float* out = (float*)d_out;

    char* ws = (char*)d_ws;
    const size_t MB8 = (size_t)8 * 1024 * 1024;
    unsigned short* qtok = (unsigned short*)(ws);              // 8 MB bf16 [n][c]
    unsigned short* ktok = (unsigned short*)(ws + MB8);        // 8 MB
    unsigned short* vtok = (unsigned short*)(ws + 2 * MB8);    // 8 MB
    unsigned short* atok = (unsigned short*)(ws + 3 * MB8);    // 8 MB
    unsigned short* xT   = (unsigned short*)(ws + 4 * MB8);    // 8 MB
    unsigned short* aT   = xT;                                 // reuse after qkv
    float*          pos  = (float*)(ws);                       // 16 MB (over q/k, post-attn)
    unsigned short* wbf  = (unsigned short*)(ws + 5 * MB8);    // 512 KB
    float*          stats= (float*)(ws + 5 * MB8 + 524288);    // 192 floats

    dim3 blk(256);
    wcvt_kernel<<<dim3(1024), blk, 0, stream>>>(wq, wk, wv, wp, wbf, stats);
    transpose_cvt_kernel<<<dim3(64, 4, 4), blk, 0, stream>>>(x, xT);
    gemm_qkv_mfma<<<dim3(2, 32, 12), blk, 0, stream>>>(wbf, xT, qtok, ktok, vtok, stats);
    attn_tok_kernel<<<dim3(512), blk, 0, stream>>>(qtok, ktok, vtok, stats,
                                                   gqg, gqb, gkg, gkb, atok);
    dwconv_fused_kernel<<<dim3(1024), blk, 0, stream>>>(x, dw1, db1, dw2, db2, pos);
    transpose_cvt_add_kernel<<<dim3(64, 4, 4), blk, 0, stream>>>(pos, atok, aT);
    gemm_out_mfma<<<dim3(32, 2, 4), blk, 0, stream>>>(wbf, aT, bp, out, stats);
    gn_apply_kernel<<<dim3(4096), blk, 0, stream>>>(out, stats, gpg, gpb);
}

// Round 6
// 183.020 us; speedup vs baseline: 1.2508x; 1.2508x over previous
//
#include <hip/hip_runtime.h>
#include <math.h>
#include <stdint.h>

#define C_ 256
#define HW_ 4096
#define PLANE (C_*HW_)   // 1048576 elements per batch
#define INV_CNT (1.f / 131072.f)
#define NSLOT 16         // atomic spread slots per (tensor,b,g)

typedef __attribute__((ext_vector_type(8))) short bf16x8;
typedef __attribute__((ext_vector_type(4))) float f32x4;

__device__ __forceinline__ unsigned short f2bf(float f) {
    union { float f; unsigned int u; } v; v.f = f;
    unsigned int r = v.u + 0x7fffu + ((v.u >> 16) & 1u);
    return (unsigned short)(r >> 16);
}

__device__ __forceinline__ void load_lds16(const void* g, void* l) {
    __builtin_amdgcn_global_load_lds(
        (const __attribute__((address_space(1))) unsigned int*)g,
        (__attribute__((address_space(3))) unsigned int*)l, 16, 0, 0);
}

// ---------------------------------------------------------------------------
// Weight convert + zero the stats buffer (3072 floats; ws is poisoned)
// ---------------------------------------------------------------------------
__global__ __launch_bounds__(256) void wcvt_kernel(
    const float* __restrict__ wq, const float* __restrict__ wk,
    const float* __restrict__ wv, const float* __restrict__ wp,
    unsigned short* __restrict__ dst, float* __restrict__ stats)
{
    int idx = blockIdx.x * 256 + threadIdx.x;   // 262144 total
    const float* s = (idx < 65536) ? wq : (idx < 131072) ? wk
                   : (idx < 196608) ? wv : wp;
    dst[idx] = f2bf(s[idx & 65535]);
    if (blockIdx.x == 0) {
#pragma unroll
        for (int i = 0; i < 12; i++) stats[threadIdx.x + i * 256] = 0.f;
    }
}

// ---------------------------------------------------------------------------
// Transpose + convert: x fp32 [b][256][4096] -> xT bf16 [b][4096][256]
// ---------------------------------------------------------------------------
__global__ __launch_bounds__(256) void transpose_cvt_kernel(
    const float* __restrict__ src, unsigned short* __restrict__ dst)
{
    __shared__ float tile[64][65];
    int b = blockIdx.z;
    const float* s = src + (size_t)b * PLANE;
    unsigned short* d = dst + (size_t)b * PLANE;
    int c0 = blockIdx.y * 64, n0 = blockIdx.x * 64;
    int t = threadIdx.x;
    int r = t >> 6, col = t & 63;
#pragma unroll
    for (int i = 0; i < 16; i++)
        tile[r + i * 4][col] = s[(size_t)(c0 + r + i * 4) * HW_ + n0 + col];
    __syncthreads();
#pragma unroll
    for (int i = 0; i < 16; i++)
        d[(size_t)(n0 + r + i * 4) * 256 + c0 + col] = f2bf(tile[col][r + i * 4]);
}

// ---------------------------------------------------------------------------
// Transpose + add attn(bf16 token-major) + convert
// ---------------------------------------------------------------------------
__global__ __launch_bounds__(256) void transpose_cvt_add_kernel(
    const float* __restrict__ pos, const unsigned short* __restrict__ attn,
    unsigned short* __restrict__ dst)
{
    __shared__ float tile[64][65];
    int b = blockIdx.z;
    const float* s = pos + (size_t)b * PLANE;
    const unsigned short* a = attn + (size_t)b * PLANE;
    unsigned short* d = dst + (size_t)b * PLANE;
    int c0 = blockIdx.y * 64, n0 = blockIdx.x * 64;
    int t = threadIdx.x;
    int r = t >> 6, col = t & 63;
#pragma unroll
    for (int i = 0; i < 16; i++)
        tile[r + i * 4][col] = s[(size_t)(c0 + r + i * 4) * HW_ + n0 + col];
    __syncthreads();
#pragma unroll
    for (int i = 0; i < 16; i++) {
        size_t o = (size_t)(n0 + r + i * 4) * 256 + c0 + col;
        float av = __uint_as_float(((unsigned)a[o]) << 16);
        d[o] = f2bf(tile[col][r + i * 4] + av);
    }
}

// ---------------------------------------------------------------------------
// MFMA core: acc[mi][ni], rows (m) from A, cols (n) from B. Both K-contig.
// ---------------------------------------------------------------------------
__device__ __forceinline__ void mfma_core(
    const unsigned short* __restrict__ A,
    const unsigned short* __restrict__ Bm,
    int m0, int n0, f32x4 (&acc)[4][4])
{
    __shared__ unsigned short As[128 * 32];
    __shared__ unsigned short Bs[128 * 32];
    const int t = threadIdx.x;
    const int lane = t & 63, wave = t >> 6;

#pragma unroll
    for (int i = 0; i < 4; i++)
#pragma unroll
        for (int j = 0; j < 4; j++) acc[i][j] = (f32x4)0.f;

    const int srow = wave * 32 + (lane >> 2);
    const int scol = (lane & 3) * 8;
    const unsigned short* ga = A  + (size_t)(m0 + srow) * 256 + scol;
    const unsigned short* gb = Bm + (size_t)(n0 + srow) * 256 + scol;
    unsigned short* la = As + (wave * 32) * 32;
    unsigned short* lb = Bs + (wave * 32) * 32;

    const int wm = wave >> 1, wn = wave & 1;
    const int fr = lane & 15, kg = lane >> 4;

    for (int k0 = 0; k0 < 256; k0 += 32) {
        if (k0) __syncthreads();
        load_lds16(ga + k0,             la);
        load_lds16(ga + k0 + 16 * 256,  la + 16 * 32);
        load_lds16(gb + k0,             lb);
        load_lds16(gb + k0 + 16 * 256,  lb + 16 * 32);
        __syncthreads();

        bf16x8 af[4], bfr[4];
#pragma unroll
        for (int i = 0; i < 4; i++) {
            af[i]  = *(const bf16x8*)(As + (wm * 64 + i * 16 + fr) * 32 + kg * 8);
            bfr[i] = *(const bf16x8*)(Bs + (wn * 64 + i * 16 + fr) * 32 + kg * 8);
        }
#pragma unroll
        for (int mi = 0; mi < 4; mi++)
#pragma unroll
            for (int ni = 0; ni < 4; ni++)
                acc[mi][ni] = __builtin_amdgcn_mfma_f32_16x16x32_bf16(
                    af[mi], bfr[ni], acc[mi][ni], 0, 0, 0);
    }
}

// wave-reduce 2 (sum,sumsq) pairs, lane 0 atomics into stats
__device__ __forceinline__ void stat_atomic(
    float s0, float ss0, float s1, float ss1, float* d0, float* d1)
{
#pragma unroll
    for (int off = 32; off >= 1; off >>= 1) {
        s0  += __shfl_down(s0, off);  ss0 += __shfl_down(ss0, off);
        s1  += __shfl_down(s1, off);  ss1 += __shfl_down(ss1, off);
    }
    if ((threadIdx.x & 63) == 0) {
        atomicAdd(d0, s0); atomicAdd(d0 + 1, ss0);
        atomicAdd(d1, s1); atomicAdd(d1 + 1, ss1);
    }
}

// sum over NSLOT spread slots for one stat set
__device__ __forceinline__ void stat_read(const float* sp, float& S, float& SS) {
    S = 0.f; SS = 0.f;
#pragma unroll
    for (int i = 0; i < NSLOT; i++) { S += sp[i * 2]; SS += sp[i * 2 + 1]; }
}

// ---------------------------------------------------------------------------
// q/k/v: A = W (outch rows) so reg dim r = consecutive outch -> uint2 stores.
// Y token-major bf16 [token][outch]. grid (2, 32, 12): x=outch-tile, y=token.
// ---------------------------------------------------------------------------
__global__ __launch_bounds__(256) void gemm_qkv_mfma(
    const unsigned short* __restrict__ wbf, const unsigned short* __restrict__ xT,
    unsigned short* __restrict__ q, unsigned short* __restrict__ k,
    unsigned short* __restrict__ v, float* __restrict__ stats)
{
    int z = blockIdx.z;
    int batch = z & 3, which = z >> 2;
    unsigned short* Y = ((which == 0) ? q : (which == 1) ? k : v)
                        + (size_t)batch * PLANE;
    const unsigned short* A  = wbf + which * 65536;          // outch x K
    const unsigned short* Bm = xT + (size_t)batch * PLANE;   // token x K
    const int m0 = blockIdx.x * 128;   // outch
    const int n0 = blockIdx.y * 128;   // token

    f32x4 acc[4][4];
    mfma_core(A, Bm, m0, n0, acc);

    const int lane = threadIdx.x & 63, wave = threadIdx.x >> 6;
    const int wm = wave >> 1, wn = wave & 1;
    const int cl = lane & 15, qd = lane >> 4;

    if (which < 2) {
        float s[2] = {0.f, 0.f}, ss[2] = {0.f, 0.f};
#pragma unroll
        for (int mi = 0; mi < 4; mi++)
#pragma unroll
            for (int ni = 0; ni < 4; ni++)
#pragma unroll
                for (int r = 0; r < 4; r++) {
                    float vv = acc[mi][ni][r];
                    s[mi >> 1] += vv; ss[mi >> 1] += vv * vv;
                }
        int g0 = (m0 >> 5) + wm * 2;
        int slot = blockIdx.y & (NSLOT - 1);
        float* d0 = stats + (size_t)(which * 32 + batch * 8 + g0) * (NSLOT * 2) + slot * 2;
        stat_atomic(s[0], ss[0], s[1], ss[1], d0, d0 + NSLOT * 2);
    }

#pragma unroll
    for (int mi = 0; mi < 4; mi++) {
        int oc = m0 + wm * 64 + mi * 16 + qd * 4;
#pragma unroll
        for (int ni = 0; ni < 4; ni++) {
            int token = n0 + wn * 64 + ni * 16 + cl;
            uint2 pk;
            pk.x = (unsigned)f2bf(acc[mi][ni][0]) | ((unsigned)f2bf(acc[mi][ni][1]) << 16);
            pk.y = (unsigned)f2bf(acc[mi][ni][2]) | ((unsigned)f2bf(acc[mi][ni][3]) << 16);
            *(uint2*)&Y[(size_t)token * 256 + oc] = pk;
        }
    }
}

// ---------------------------------------------------------------------------
// final projection: A = aT (token rows) -> r = consecutive tokens -> float4.
// Y channel-major fp32 [outch][token]. grid (32, 2, 4): x=token-tile, y=outch.
// ---------------------------------------------------------------------------
__global__ __launch_bounds__(256) void gemm_out_mfma(
    const unsigned short* __restrict__ wbf, const unsigned short* __restrict__ aT,
    const float* __restrict__ bp, float* __restrict__ y, float* __restrict__ stats)
{
    int batch = blockIdx.z;
    const unsigned short* A  = aT + (size_t)batch * PLANE;   // token x K
    const unsigned short* Bm = wbf + 3 * 65536;              // outch x K
    float* Y = y + (size_t)batch * PLANE;
    const int m0 = blockIdx.x * 128;   // token
    const int n0 = blockIdx.y * 128;   // outch

    f32x4 acc[4][4];
    mfma_core(A, Bm, m0, n0, acc);

    const int lane = threadIdx.x & 63, wave = threadIdx.x >> 6;
    const int wm = wave >> 1, wn = wave & 1;
    const int cl = lane & 15, qd = lane >> 4;

    float s[2] = {0.f, 0.f}, ss[2] = {0.f, 0.f};
#pragma unroll
    for (int ni = 0; ni < 4; ni++) {
        int oc = n0 + wn * 64 + ni * 16 + cl;
        float bb = bp[oc];
#pragma unroll
        for (int mi = 0; mi < 4; mi++) {
            int tk = m0 + wm * 64 + mi * 16 + qd * 4;
            float4 o;
            o.x = acc[mi][ni][0] + bb; o.y = acc[mi][ni][1] + bb;
            o.z = acc[mi][ni][2] + bb; o.w = acc[mi][ni][3] + bb;
            s[ni >> 1] += o.x + o.y + o.z + o.w;
            ss[ni >> 1] += o.x * o.x + o.y * o.y + o.z * o.z + o.w * o.w;
            *(float4*)&Y[(size_t)oc * HW_ + tk] = o;
        }
    }
    int g0 = (n0 >> 5) + wn * 2;
    int slot = blockIdx.x & (NSLOT - 1);
    float* d0 = stats + (size_t)(64 + batch * 8 + g0) * (NSLOT * 2) + slot * 2;
    stat_atomic(s[0], ss[0], s[1], ss[1], d0, d0 + NSLOT * 2);
}

// ---------------------------------------------------------------------------
// Attention, token-major bf16 in/out. Thread = one (pixel, head).
// ---------------------------------------------------------------------------
__device__ __forceinline__ void bf16x32_load(const unsigned short* p, float* o) {
    const uint4* u4 = (const uint4*)p;
#pragma unroll
    for (int i = 0; i < 4; i++) {
        uint4 u = u4[i];
        o[i*8+0] = __uint_as_float(u.x << 16); o[i*8+1] = __uint_as_float(u.x & 0xffff0000u);
        o[i*8+2] = __uint_as_float(u.y << 16); o[i*8+3] = __uint_as_float(u.y & 0xffff0000u);
        o[i*8+4] = __uint_as_float(u.z << 16); o[i*8+5] = __uint_as_float(u.z & 0xffff0000u);
        o[i*8+6] = __uint_as_float(u.w << 16); o[i*8+7] = __uint_as_float(u.w & 0xffff0000u);
    }
}

__global__ __launch_bounds__(256) void attn_tok_kernel(
    const unsigned short* __restrict__ qtok, const unsigned short* __restrict__ ktok,
    const unsigned short* __restrict__ vtok, const float* __restrict__ stats,
    const float* __restrict__ gqg, const float* __restrict__ gqb,
    const float* __restrict__ gkg, const float* __restrict__ gkb,
    unsigned short* __restrict__ out)
{
    __shared__ float sqg[256], sqb[256], skg[256], skb[256];
    const int t = threadIdx.x;
    sqg[t] = gqg[t]; sqb[t] = gqb[t]; skg[t] = gkg[t]; skb[t] = gkb[t];
    __syncthreads();

    const int h = t & 7;
    const int pix = blockIdx.x * 32 + (t >> 3);   // 0..16383
    const int b = pix >> 12;
    const size_t base = (size_t)pix * 256 + h * 32;
    const float K2 = 0.17677669529663687f * 1.4426950408889634f; // scale*log2e

    float a[32], kn[32], vv[32];

    // Q
    {
        float S, SS;
        stat_read(stats + (size_t)(b * 8 + h) * (NSLOT * 2), S, SS);
        float m = S * INV_CNT;
        float r = rsqrtf(SS * INV_CNT - m * m + 1e-5f);
        float qv[32], ssum = 0.f;
        bf16x32_load(qtok + base, qv);
#pragma unroll
        for (int j = 0; j < 32; j++) {
            float g = r * sqg[h * 32 + j];
            qv[j] = (qv[j] - m) * g + sqb[h * 32 + j];
            ssum = fmaf(qv[j], qv[j], ssum);
        }
        float inv = K2 / fmaxf(sqrtf(ssum), 1e-12f);
#pragma unroll
        for (int j = 0; j < 32; j++) a[j] = qv[j] * inv;
    }
    // K
    {
        float S, SS;
        stat_read(stats + (size_t)(32 + b * 8 + h) * (NSLOT * 2), S, SS);
        float m = S * INV_CNT;
        float r = rsqrtf(SS * INV_CNT - m * m + 1e-5f);
        float ssum = 0.f;
        bf16x32_load(ktok + base, kn);
#pragma unroll
        for (int j = 0; j < 32; j++) {
            float g = r * skg[h * 32 + j];
            kn[j] = (kn[j] - m) * g + skb[h * 32 + j];
            ssum = fmaf(kn[j], kn[j], ssum);
        }
        float inv = 1.f / fmaxf(sqrtf(ssum), 1e-12f);
#pragma unroll
        for (int j = 0; j < 32; j++) kn[j] *= inv;
    }
    bf16x32_load(vtok + base, vv);

    uint4* op = (uint4*)(out + base);
#pragma unroll
    for (int di = 0; di < 4; di++) {
        unsigned int od[4];
#pragma unroll
        for (int dp = 0; dp < 4; dp++) {
            float o2[2];
#pragma unroll
            for (int dd = 0; dd < 2; dd++) {
                float ad = a[di * 8 + dp * 2 + dd];
                float num = 0.f, den = 0.f;
#pragma unroll
                for (int e = 0; e < 32; e++) {
                    float w = __builtin_amdgcn_exp2f(ad * kn[e]);
                    num = fmaf(w, vv[e], num);
                    den += w;
                }
                o2[dd] = num / den;
            }
            od[dp] = (unsigned)f2bf(o2[0]) | ((unsigned)f2bf(o2[1]) << 16);
        }
        op[di] = make_uint4(od[0], od[1], od[2], od[3]);
    }
}

// ---------------------------------------------------------------------------
// Fused depthwise 3x3 -> GELU -> depthwise 3x3. One (b,c) plane per block.
// ---------------------------------------------------------------------------
__device__ __forceinline__ float gelu_exact(float v) {
    return 0.5f * v * (1.f + erff(v * 0.70710678118654752f));
}

__global__ __launch_bounds__(256) void dwconv_fused_kernel(
    const float* __restrict__ x,
    const float* __restrict__ dw1, const float* __restrict__ db1,
    const float* __restrict__ dw2, const float* __restrict__ db2,
    float* __restrict__ pos)
{
    __shared__ float xs[66 * 68];
    __shared__ float ps[66 * 68];
    const int bc = blockIdx.x;      // b*256 + c
    const int c = bc & 255;
    const int t = threadIdx.x;
    const float* plane = x + (size_t)bc * 4096;

    float w1[9], w2[9];
#pragma unroll
    for (int i = 0; i < 9; i++) { w1[i] = dw1[c * 9 + i]; w2[i] = dw2[c * 9 + i]; }
    const float b1 = db1[c], b2 = db2[c];

    for (int i = t; i < 66 * 66; i += 256) {
        int r = i / 66, cc = i - r * 66;
        int gr = r - 1, gc = cc - 1;
        float v = 0.f;
        if ((unsigned)gr < 64u && (unsigned)gc < 64u) v = plane[gr * 64 + gc];
        xs[r * 68 + cc] = v;
    }
    __syncthreads();

    for (int i = t; i < 66 * 66; i += 256) {
        int pr = i / 66, pc = i - pr * 66;
        int gr = pr - 1, gc = pc - 1;
        float val = 0.f;
        if ((unsigned)gr < 64u && (unsigned)gc < 64u) {
            float s = b1;
#pragma unroll
            for (int ky = 0; ky < 3; ky++)
#pragma unroll
                for (int kx = 0; kx < 3; kx++)
                    s += w1[ky * 3 + kx] * xs[(gr + ky) * 68 + (gc + kx)];
            val = gelu_exact(s);
        }
        ps[pr * 68 + pc] = val;
    }
    __syncthreads();

    for (int i = t; i < 4096; i += 256) {
        int orow = i >> 6, ocol = i & 63;
        float s = b2;
#pragma unroll
        for (int ky = 0; ky < 3; ky++)
#pragma unroll
            for (int kx = 0; kx < 3; kx++)
                s += w2[ky * 3 + kx] * ps[(orow + ky) * 68 + (ocol + kx)];
        pos[(size_t)bc * 4096 + i] = s;
    }
}

// ---------------------------------------------------------------------------
// Final GroupNorm apply (in place on d_out), mean/rstd from spread sums
// ---------------------------------------------------------------------------
__global__ __launch_bounds__(256) void gn_apply_kernel(
    float* __restrict__ y, const float* __restrict__ stats,
    const float* __restrict__ gamma, const float* __restrict__ beta)
{
    int i4 = blockIdx.x * 256 + threadIdx.x;
    int idx = i4 * 4;
    int c = (idx >> 12) & 255;
    int bg = ((idx >> 20) << 3) | (c >> 5);
    float S, SS;
    stat_read(stats + (size_t)(64 + bg) * (NSLOT * 2), S, SS);
    float mean = S * INV_CNT;
    float rstd = rsqrtf(SS * INV_CNT - mean * mean + 1e-5f);
    float ga = rstd * gamma[c], be = beta[c] - mean * ga;
    float4 v4 = *(float4*)&y[idx];
    v4.x = v4.x * ga + be;
    v4.y = v4.y * ga + be;
    v4.z = v4.z * ga + be;
    v4.w = v4.w * ga + be;
    *(float4*)&y[idx] = v4;
}

// ---------------------------------------------------------------------------
extern "C" void kernel_launch(void* const* d_in, const int* in_sizes, int n_in,
                              void* d_out, int out_size, void* d_ws, size_t ws_size,
                              hipStream_t stream)
{
    const float* x   = (const float*)d_in[0];
    const float* wq  = (const float*)d_in[1];
    const float* gqg = (const float*)d_in[2];
    const float* gqb = (const float*)d_in[3];
    const float* wk  = (const float*)d_in[4];
    const float* gkg = (const float*)d_in[5];
    const float* gkb = (const float*)d_in[6];
    const float* wv  = (const float*)d_in[7];
    const float* wp  = (const float*)d_in[8];
    const float* bp  = (const float*)d_in[9];
    const float* gpg = (const float*)d_in[10];
    const float* gpb = (const float*)d_in[11];
    const float* dw1 = (const float*)d_in[12];
    const float* db1 = (const float*)d_in[13];
    const float* dw2 = (const float*)d_in[14];
    const float* db2 = (const float*)d_in[15];
    float* out = (float*)d_out;

    char* ws = (char*)d_ws;
    const size_t MB8 = (size_t)8 * 1024 * 1024;
    unsigned short* qtok = (unsigned short*)(ws);              // 8 MB bf16 [n][c]
    unsigned short* ktok = (unsigned short*)(ws + MB8);        // 8 MB
    unsigned short* vtok = (unsigned short*)(ws + 2 * MB8);    // 8 MB
    unsigned short* atok = (unsigned short*)(ws + 3 * MB8);    // 8 MB
    unsigned short* xT   = (unsigned short*)(ws + 4 * MB8);    // 8 MB
    unsigned short* aT   = xT;                                 // reuse after qkv
    float*          pos  = (float*)(ws);                       // 16 MB (over q/k, post-attn)
    unsigned short* wbf  = (unsigned short*)(ws + 5 * MB8);    // 512 KB
    float*          stats= (float*)(ws + 5 * MB8 + 524288);    // 3072 floats

    dim3 blk(256);
    wcvt_kernel<<<dim3(1024), blk, 0, stream>>>(wq, wk, wv, wp, wbf, stats);
    transpose_cvt_kernel<<<dim3(64, 4, 4), blk, 0, stream>>>(x, xT);
    gemm_qkv_mfma<<<dim3(2, 32, 12), blk, 0, stream>>>(wbf, xT, qtok, ktok, vtok, stats);
    attn_tok_kernel<<<dim3(512), blk, 0, stream>>>(qtok, ktok, vtok, stats,
                                                   gqg, gqb, gkg, gkb, atok);
    dwconv_fused_kernel<<<dim3(1024), blk, 0, stream>>>(x, dw1, db1, dw2, db2, pos);
    transpose_cvt_add_kernel<<<dim3(64, 4, 4), blk, 0, stream>>>(pos, atok, aT);
    gemm_out_mfma<<<dim3(32, 2, 4), blk, 0, stream>>>(wbf, aT, bp, out, stats);
    gn_apply_kernel<<<dim3(4096), blk, 0, stream>>>(out, stats, gpg, gpb);
}

// Round 7
// 177.910 us; speedup vs baseline: 1.2867x; 1.0287x over previous
//
#include <hip/hip_runtime.h>
#include <math.h>
#include <stdint.h>

#define C_ 256
#define HW_ 4096
#define PLANE (C_*HW_)   // 1048576 elements per batch
#define INV_CNT (1.f / 131072.f)
#define NSLOT 16         // atomic spread slots per (tensor,b,g)

typedef __attribute__((ext_vector_type(8))) short bf16x8;
typedef __attribute__((ext_vector_type(4))) float f32x4;

__device__ __forceinline__ unsigned short f2bf(float f) {
    union { float f; unsigned int u; } v; v.f = f;
    unsigned int r = v.u + 0x7fffu + ((v.u >> 16) & 1u);
    return (unsigned short)(r >> 16);
}

__device__ __forceinline__ float bf2f(unsigned short u) {
    return __uint_as_float(((unsigned)u) << 16);
}

__device__ __forceinline__ void load_lds16(const void* g, void* l) {
    __builtin_amdgcn_global_load_lds(
        (const __attribute__((address_space(1))) unsigned int*)g,
        (__attribute__((address_space(3))) unsigned int*)l, 16, 0, 0);
}

// ---------------------------------------------------------------------------
// Transpose + convert: x fp32 [b][256][4096] -> xT bf16 [b][4096][256].
// Also absorbs weight conversion (4x 256x256 fp32 -> bf16) and stats zeroing.
// grid (64, 4, 4)
// ---------------------------------------------------------------------------
__global__ __launch_bounds__(256) void transpose_cvt_kernel(
    const float* __restrict__ src, unsigned short* __restrict__ dst,
    const float* __restrict__ wq, const float* __restrict__ wk,
    const float* __restrict__ wv, const float* __restrict__ wp,
    unsigned short* __restrict__ wbf, float* __restrict__ stats)
{
    __shared__ float tile[64][65];
    int t = threadIdx.x;

    // --- weight convert: one 256-element chunk per block ---
    int bid = blockIdx.x + 64 * (blockIdx.y + 4 * blockIdx.z);   // 0..1023
    {
        int widx = bid * 256 + t;
        const float* s = (widx < 65536) ? wq : (widx < 131072) ? wk
                       : (widx < 196608) ? wv : wp;
        wbf[widx] = f2bf(s[widx & 65535]);
        if (bid == 0) {
#pragma unroll
            for (int i = 0; i < 12; i++) stats[t + i * 256] = 0.f;
        }
    }

    // --- transpose ---
    int b = blockIdx.z;
    const float* s = src + (size_t)b * PLANE;
    unsigned short* d = dst + (size_t)b * PLANE;
    int c0 = blockIdx.y * 64, n0 = blockIdx.x * 64;
    int r = t >> 6, col = t & 63;
#pragma unroll
    for (int i = 0; i < 16; i++)
        tile[r + i * 4][col] = s[(size_t)(c0 + r + i * 4) * HW_ + n0 + col];
    __syncthreads();
#pragma unroll
    for (int i = 0; i < 16; i++)
        d[(size_t)(n0 + r + i * 4) * 256 + c0 + col] = f2bf(tile[col][r + i * 4]);
}

// ---------------------------------------------------------------------------
// Transpose + add attn(bf16 token-major) + convert: aT = bf16(pos^T + atok)
// pos is bf16 channel-major. grid (64, 4, 4)
// ---------------------------------------------------------------------------
__global__ __launch_bounds__(256) void transpose_cvt_add_kernel(
    const unsigned short* __restrict__ pos, const unsigned short* __restrict__ attn,
    unsigned short* __restrict__ dst)
{
    __shared__ float tile[64][65];
    int b = blockIdx.z;
    const unsigned short* s = pos + (size_t)b * PLANE;
    const unsigned short* a = attn + (size_t)b * PLANE;
    unsigned short* d = dst + (size_t)b * PLANE;
    int c0 = blockIdx.y * 64, n0 = blockIdx.x * 64;
    int t = threadIdx.x;
    int r = t >> 6, col = t & 63;
#pragma unroll
    for (int i = 0; i < 16; i++)
        tile[r + i * 4][col] = bf2f(s[(size_t)(c0 + r + i * 4) * HW_ + n0 + col]);
    __syncthreads();
#pragma unroll
    for (int i = 0; i < 16; i++) {
        size_t o = (size_t)(n0 + r + i * 4) * 256 + c0 + col;
        d[o] = f2bf(tile[col][r + i * 4] + bf2f(a[o]));
    }
}

// ---------------------------------------------------------------------------
// MFMA core, BK=64 as two BK=32 sub-buffers (same LDS addressing as BK=32,
// so global_load_lds lane mapping and bank behavior are unchanged).
// 4 K-iterations, 32 MFMA per barrier-pair. LDS 32 KB.
// ---------------------------------------------------------------------------
__device__ __forceinline__ void mfma_core(
    const unsigned short* __restrict__ A,
    const unsigned short* __restrict__ Bm,
    int m0, int n0, f32x4 (&acc)[4][4])
{
    __shared__ unsigned short As[2][128 * 32];
    __shared__ unsigned short Bs[2][128 * 32];
    const int t = threadIdx.x;
    const int lane = t & 63, wave = t >> 6;

#pragma unroll
    for (int i = 0; i < 4; i++)
#pragma unroll
        for (int j = 0; j < 4; j++) acc[i][j] = (f32x4)0.f;

    const int srow = wave * 32 + (lane >> 2);
    const int scol = (lane & 3) * 8;
    const unsigned short* ga = A  + (size_t)(m0 + srow) * 256 + scol;
    const unsigned short* gb = Bm + (size_t)(n0 + srow) * 256 + scol;
    const int lbase = (wave * 32) * 32;

    const int wm = wave >> 1, wn = wave & 1;
    const int fr = lane & 15, kg = lane >> 4;

    for (int k0 = 0; k0 < 256; k0 += 64) {
        if (k0) __syncthreads();
        // sub-buffer 0: K in [k0, k0+32)
        load_lds16(ga + k0,            As[0] + lbase);
        load_lds16(ga + k0 + 16 * 256, As[0] + lbase + 16 * 32);
        load_lds16(gb + k0,            Bs[0] + lbase);
        load_lds16(gb + k0 + 16 * 256, Bs[0] + lbase + 16 * 32);
        // sub-buffer 1: K in [k0+32, k0+64)
        load_lds16(ga + k0 + 32,            As[1] + lbase);
        load_lds16(ga + k0 + 32 + 16 * 256, As[1] + lbase + 16 * 32);
        load_lds16(gb + k0 + 32,            Bs[1] + lbase);
        load_lds16(gb + k0 + 32 + 16 * 256, Bs[1] + lbase + 16 * 32);
        __syncthreads();

#pragma unroll
        for (int kk = 0; kk < 2; kk++) {
            bf16x8 af[4], bfr[4];
#pragma unroll
            for (int i = 0; i < 4; i++) {
                af[i]  = *(const bf16x8*)(As[kk] + (wm * 64 + i * 16 + fr) * 32 + kg * 8);
                bfr[i] = *(const bf16x8*)(Bs[kk] + (wn * 64 + i * 16 + fr) * 32 + kg * 8);
            }
#pragma unroll
            for (int mi = 0; mi < 4; mi++)
#pragma unroll
                for (int ni = 0; ni < 4; ni++)
                    acc[mi][ni] = __builtin_amdgcn_mfma_f32_16x16x32_bf16(
                        af[mi], bfr[ni], acc[mi][ni], 0, 0, 0);
        }
    }
}

// wave-reduce 2 (sum,sumsq) pairs, lane 0 atomics into stats
__device__ __forceinline__ void stat_atomic(
    float s0, float ss0, float s1, float ss1, float* d0, float* d1)
{
#pragma unroll
    for (int off = 32; off >= 1; off >>= 1) {
        s0  += __shfl_down(s0, off);  ss0 += __shfl_down(ss0, off);
        s1  += __shfl_down(s1, off);  ss1 += __shfl_down(ss1, off);
    }
    if ((threadIdx.x & 63) == 0) {
        atomicAdd(d0, s0); atomicAdd(d0 + 1, ss0);
        atomicAdd(d1, s1); atomicAdd(d1 + 1, ss1);
    }
}

__device__ __forceinline__ void stat_read(const float* sp, float& S, float& SS) {
    S = 0.f; SS = 0.f;
#pragma unroll
    for (int i = 0; i < NSLOT; i++) { S += sp[i * 2]; SS += sp[i * 2 + 1]; }
}

// ---------------------------------------------------------------------------
// q/k/v: A = W (outch rows) -> reg dim r = consecutive outch -> uint2 stores.
// Y token-major bf16 [token][outch]. grid (2, 32, 12): x=outch-tile, y=token.
// ---------------------------------------------------------------------------
__global__ __launch_bounds__(256) void gemm_qkv_mfma(
    const unsigned short* __restrict__ wbf, const unsigned short* __restrict__ xT,
    unsigned short* __restrict__ q, unsigned short* __restrict__ k,
    unsigned short* __restrict__ v, float* __restrict__ stats)
{
    int z = blockIdx.z;
    int batch = z & 3, which = z >> 2;
    unsigned short* Y = ((which == 0) ? q : (which == 1) ? k : v)
                        + (size_t)batch * PLANE;
    const unsigned short* A  = wbf + which * 65536;          // outch x K
    const unsigned short* Bm = xT + (size_t)batch * PLANE;   // token x K
    const int m0 = blockIdx.x * 128;   // outch
    const int n0 = blockIdx.y * 128;   // token

    f32x4 acc[4][4];
    mfma_core(A, Bm, m0, n0, acc);

    const int lane = threadIdx.x & 63, wave = threadIdx.x >> 6;
    const int wm = wave >> 1, wn = wave & 1;
    const int cl = lane & 15, qd = lane >> 4;

    if (which < 2) {
        float s[2] = {0.f, 0.f}, ss[2] = {0.f, 0.f};
#pragma unroll
        for (int mi = 0; mi < 4; mi++)
#pragma unroll
            for (int ni = 0; ni < 4; ni++)
#pragma unroll
                for (int r = 0; r < 4; r++) {
                    float vv = acc[mi][ni][r];
                    s[mi >> 1] += vv; ss[mi >> 1] += vv * vv;
                }
        int g0 = (m0 >> 5) + wm * 2;
        int slot = blockIdx.y & (NSLOT - 1);
        float* d0 = stats + (size_t)(which * 32 + batch * 8 + g0) * (NSLOT * 2) + slot * 2;
        stat_atomic(s[0], ss[0], s[1], ss[1], d0, d0 + NSLOT * 2);
    }

#pragma unroll
    for (int mi = 0; mi < 4; mi++) {
        int oc = m0 + wm * 64 + mi * 16 + qd * 4;
#pragma unroll
        for (int ni = 0; ni < 4; ni++) {
            int token = n0 + wn * 64 + ni * 16 + cl;
            uint2 pk;
            pk.x = (unsigned)f2bf(acc[mi][ni][0]) | ((unsigned)f2bf(acc[mi][ni][1]) << 16);
            pk.y = (unsigned)f2bf(acc[mi][ni][2]) | ((unsigned)f2bf(acc[mi][ni][3]) << 16);
            *(uint2*)&Y[(size_t)token * 256 + oc] = pk;
        }
    }
}

// ---------------------------------------------------------------------------
// final projection: A = aT (token rows) -> r = consecutive tokens -> float4.
// Y channel-major fp32 [outch][token]. grid (32, 2, 4): x=token-tile, y=outch.
// ---------------------------------------------------------------------------
__global__ __launch_bounds__(256) void gemm_out_mfma(
    const unsigned short* __restrict__ wbf, const unsigned short* __restrict__ aT,
    const float* __restrict__ bp, float* __restrict__ y, float* __restrict__ stats)
{
    int batch = blockIdx.z;
    const unsigned short* A  = aT + (size_t)batch * PLANE;   // token x K
    const unsigned short* Bm = wbf + 3 * 65536;              // outch x K
    float* Y = y + (size_t)batch * PLANE;
    const int m0 = blockIdx.x * 128;   // token
    const int n0 = blockIdx.y * 128;   // outch

    f32x4 acc[4][4];
    mfma_core(A, Bm, m0, n0, acc);

    const int lane = threadIdx.x & 63, wave = threadIdx.x >> 6;
    const int wm = wave >> 1, wn = wave & 1;
    const int cl = lane & 15, qd = lane >> 4;

    float s[2] = {0.f, 0.f}, ss[2] = {0.f, 0.f};
#pragma unroll
    for (int ni = 0; ni < 4; ni++) {
        int oc = n0 + wn * 64 + ni * 16 + cl;
        float bb = bp[oc];
#pragma unroll
        for (int mi = 0; mi < 4; mi++) {
            int tk = m0 + wm * 64 + mi * 16 + qd * 4;
            float4 o;
            o.x = acc[mi][ni][0] + bb; o.y = acc[mi][ni][1] + bb;
            o.z = acc[mi][ni][2] + bb; o.w = acc[mi][ni][3] + bb;
            s[ni >> 1] += o.x + o.y + o.z + o.w;
            ss[ni >> 1] += o.x * o.x + o.y * o.y + o.z * o.z + o.w * o.w;
            *(float4*)&Y[(size_t)oc * HW_ + tk] = o;
        }
    }
    int g0 = (n0 >> 5) + wn * 2;
    int slot = blockIdx.x & (NSLOT - 1);
    float* d0 = stats + (size_t)(64 + batch * 8 + g0) * (NSLOT * 2) + slot * 2;
    stat_atomic(s[0], ss[0], s[1], ss[1], d0, d0 + NSLOT * 2);
}

// ---------------------------------------------------------------------------
// Attention, token-major bf16 in/out. Thread = one (pixel, head).
// ---------------------------------------------------------------------------
__device__ __forceinline__ void bf16x32_load(const unsigned short* p, float* o) {
    const uint4* u4 = (const uint4*)p;
#pragma unroll
    for (int i = 0; i < 4; i++) {
        uint4 u = u4[i];
        o[i*8+0] = __uint_as_float(u.x << 16); o[i*8+1] = __uint_as_float(u.x & 0xffff0000u);
        o[i*8+2] = __uint_as_float(u.y << 16); o[i*8+3] = __uint_as_float(u.y & 0xffff0000u);
        o[i*8+4] = __uint_as_float(u.z << 16); o[i*8+5] = __uint_as_float(u.z & 0xffff0000u);
        o[i*8+6] = __uint_as_float(u.w << 16); o[i*8+7] = __uint_as_float(u.w & 0xffff0000u);
    }
}

__global__ __launch_bounds__(256) void attn_tok_kernel(
    const unsigned short* __restrict__ qtok, const unsigned short* __restrict__ ktok,
    const unsigned short* __restrict__ vtok, const float* __restrict__ stats,
    const float* __restrict__ gqg, const float* __restrict__ gqb,
    const float* __restrict__ gkg, const float* __restrict__ gkb,
    unsigned short* __restrict__ out)
{
    __shared__ float sqg[256], sqb[256], skg[256], skb[256];
    const int t = threadIdx.x;
    sqg[t] = gqg[t]; sqb[t] = gqb[t]; skg[t] = gkg[t]; skb[t] = gkb[t];
    __syncthreads();

    const int h = t & 7;
    const int pix = blockIdx.x * 32 + (t >> 3);   // 0..16383
    const int b = pix >> 12;
    const size_t base = (size_t)pix * 256 + h * 32;
    const float K2 = 0.17677669529663687f * 1.4426950408889634f; // scale*log2e

    float a[32], kn[32], vv[32];

    // Q
    {
        float S, SS;
        stat_read(stats + (size_t)(b * 8 + h) * (NSLOT * 2), S, SS);
        float m = S * INV_CNT;
        float r = rsqrtf(SS * INV_CNT - m * m + 1e-5f);
        float qv[32], ssum = 0.f;
        bf16x32_load(qtok + base, qv);
#pragma unroll
        for (int j = 0; j < 32; j++) {
            float g = r * sqg[h * 32 + j];
            qv[j] = (qv[j] - m) * g + sqb[h * 32 + j];
            ssum = fmaf(qv[j], qv[j], ssum);
        }
        float inv = K2 / fmaxf(sqrtf(ssum), 1e-12f);
#pragma unroll
        for (int j = 0; j < 32; j++) a[j] = qv[j] * inv;
    }
    // K
    {
        float S, SS;
        stat_read(stats + (size_t)(32 + b * 8 + h) * (NSLOT * 2), S, SS);
        float m = S * INV_CNT;
        float r = rsqrtf(SS * INV_CNT - m * m + 1e-5f);
        float ssum = 0.f;
        bf16x32_load(ktok + base, kn);
#pragma unroll
        for (int j = 0; j < 32; j++) {
            float g = r * skg[h * 32 + j];
            kn[j] = (kn[j] - m) * g + skb[h * 32 + j];
            ssum = fmaf(kn[j], kn[j], ssum);
        }
        float inv = 1.f / fmaxf(sqrtf(ssum), 1e-12f);
#pragma unroll
        for (int j = 0; j < 32; j++) kn[j] *= inv;
    }
    bf16x32_load(vtok + base, vv);

    uint4* op = (uint4*)(out + base);
#pragma unroll
    for (int di = 0; di < 4; di++) {
        unsigned int od[4];
#pragma unroll
        for (int dp = 0; dp < 4; dp++) {
            float o2[2];
#pragma unroll
            for (int dd = 0; dd < 2; dd++) {
                float ad = a[di * 8 + dp * 2 + dd];
                float num = 0.f, den = 0.f;
#pragma unroll
                for (int e = 0; e < 32; e++) {
                    float w = __builtin_amdgcn_exp2f(ad * kn[e]);
                    num = fmaf(w, vv[e], num);
                    den += w;
                }
                o2[dd] = num / den;
            }
            od[dp] = (unsigned)f2bf(o2[0]) | ((unsigned)f2bf(o2[1]) << 16);
        }
        op[di] = make_uint4(od[0], od[1], od[2], od[3]);
    }
}

// ---------------------------------------------------------------------------
// Fused depthwise 3x3 -> GELU -> depthwise 3x3 -> bf16. One (b,c) plane/block.
// ---------------------------------------------------------------------------
__device__ __forceinline__ float gelu_exact(float v) {
    return 0.5f * v * (1.f + erff(v * 0.70710678118654752f));
}

__global__ __launch_bounds__(256) void dwconv_fused_kernel(
    const float* __restrict__ x,
    const float* __restrict__ dw1, const float* __restrict__ db1,
    const float* __restrict__ dw2, const float* __restrict__ db2,
    unsigned short* __restrict__ pos)
{
    __shared__ float xs[66 * 68];
    __shared__ float ps[66 * 68];
    const int bc = blockIdx.x;      // b*256 + c
    const int c = bc & 255;
    const int t = threadIdx.x;
    const float* plane = x + (size_t)bc * 4096;

    float w1[9], w2[9];
#pragma unroll
    for (int i = 0; i < 9; i++) { w1[i] = dw1[c * 9 + i]; w2[i] = dw2[c * 9 + i]; }
    const float b1 = db1[c], b2 = db2[c];

    for (int i = t; i < 66 * 66; i += 256) {
        int r = i / 66, cc = i - r * 66;
        int gr = r - 1, gc = cc - 1;
        float v = 0.f;
        if ((unsigned)gr < 64u && (unsigned)gc < 64u) v = plane[gr * 64 + gc];
        xs[r * 68 + cc] = v;
    }
    __syncthreads();

    for (int i = t; i < 66 * 66; i += 256) {
        int pr = i / 66, pc = i - pr * 66;
        int gr = pr - 1, gc = pc - 1;
        float val = 0.f;
        if ((unsigned)gr < 64u && (unsigned)gc < 64u) {
            float s = b1;
#pragma unroll
            for (int ky = 0; ky < 3; ky++)
#pragma unroll
                for (int kx = 0; kx < 3; kx++)
                    s += w1[ky * 3 + kx] * xs[(gr + ky) * 68 + (gc + kx)];
            val = gelu_exact(s);
        }
        ps[pr * 68 + pc] = val;
    }
    __syncthreads();

    for (int i = t; i < 4096; i += 256) {
        int orow = i >> 6, ocol = i & 63;
        float s = b2;
#pragma unroll
        for (int ky = 0; ky < 3; ky++)
#pragma unroll
            for (int kx = 0; kx < 3; kx++)
                s += w2[ky * 3 + kx] * ps[(orow + ky) * 68 + (ocol + kx)];
        pos[(size_t)bc * 4096 + i] = f2bf(s);
    }
}

// ---------------------------------------------------------------------------
// Final GroupNorm apply (in place on d_out), mean/rstd from spread sums
// ---------------------------------------------------------------------------
__global__ __launch_bounds__(256) void gn_apply_kernel(
    float* __restrict__ y, const float* __restrict__ stats,
    const float* __restrict__ gamma, const float* __restrict__ beta)
{
    int i4 = blockIdx.x * 256 + threadIdx.x;
    int idx = i4 * 4;
    int c = (idx >> 12) & 255;
    int bg = ((idx >> 20) << 3) | (c >> 5);
    float S, SS;
    stat_read(stats + (size_t)(64 + bg) * (NSLOT * 2), S, SS);
    float mean = S * INV_CNT;
    float rstd = rsqrtf(SS * INV_CNT - mean * mean + 1e-5f);
    float ga = rstd * gamma[c], be = beta[c] - mean * ga;
    float4 v4 = *(float4*)&y[idx];
    v4.x = v4.x * ga + be;
    v4.y = v4.y * ga + be;
    v4.z = v4.z * ga + be;
    v4.w = v4.w * ga + be;
    *(float4*)&y[idx] = v4;
}

// ---------------------------------------------------------------------------
extern "C" void kernel_launch(void* const* d_in, const int* in_sizes, int n_in,
                              void* d_out, int out_size, void* d_ws, size_t ws_size,
                              hipStream_t stream)
{
    const float* x   = (const float*)d_in[0];
    const float* wq  = (const float*)d_in[1];
    const float* gqg = (const float*)d_in[2];
    const float* gqb = (const float*)d_in[3];
    const float* wk  = (const float*)d_in[4];
    const float* gkg = (const float*)d_in[5];
    const float* gkb = (const float*)d_in[6];
    const float* wv  = (const float*)d_in[7];
    const float* wp  = (const float*)d_in[8];
    const float* bp  = (const float*)d_in[9];
    const float* gpg = (const float*)d_in[10];
    const float* gpb = (const float*)d_in[11];
    const float* dw1 = (const float*)d_in[12];
    const float* db1 = (const float*)d_in[13];
    const float* dw2 = (const float*)d_in[14];
    const float* db2 = (const float*)d_in[15];
    float* out = (float*)d_out;

    char* ws = (char*)d_ws;
    const size_t MB8 = (size_t)8 * 1024 * 1024;
    unsigned short* qtok = (unsigned short*)(ws);              // 8 MB bf16 [n][c]
    unsigned short* ktok = (unsigned short*)(ws + MB8);        // 8 MB
    unsigned short* vtok = (unsigned short*)(ws + 2 * MB8);    // 8 MB
    unsigned short* atok = (unsigned short*)(ws + 3 * MB8);    // 8 MB
    unsigned short* xT   = (unsigned short*)(ws + 4 * MB8);    // 8 MB
    unsigned short* aT   = xT;                                 // reuse after qkv
    unsigned short* pos  = qtok;                               // 8 MB bf16, reuse (attn consumed q)
    unsigned short* wbf  = (unsigned short*)(ws + 5 * MB8);    // 512 KB
    float*          stats= (float*)(ws + 5 * MB8 + 524288);    // 3072 floats

    dim3 blk(256);
    transpose_cvt_kernel<<<dim3(64, 4, 4), blk, 0, stream>>>(x, xT, wq, wk, wv, wp, wbf, stats);
    gemm_qkv_mfma<<<dim3(2, 32, 12), blk, 0, stream>>>(wbf, xT, qtok, ktok, vtok, stats);
    attn_tok_kernel<<<dim3(512), blk, 0, stream>>>(qtok, ktok, vtok, stats,
                                                   gqg, gqb, gkg, gkb, atok);
    dwconv_fused_kernel<<<dim3(1024), blk, 0, stream>>>(x, dw1, db1, dw2, db2, pos);
    transpose_cvt_add_kernel<<<dim3(64, 4, 4), blk, 0, stream>>>(pos, atok, aT);
    gemm_out_mfma<<<dim3(32, 2, 4), blk, 0, stream>>>(wbf, aT, bp, out, stats);
    gn_apply_kernel<<<dim3(4096), blk, 0, stream>>>(out, stats, gpg, gpb);
}